// Round 13
// baseline (154.741 us; speedup 1.0000x reference)
//
#include <hip/hip_runtime.h>
#include <math.h>

// S4 forward, collapsed: out depends only on conv output at t = L-1.
// P[b,h] = sum_l kk[h,l]*u[b,h,l] + D[h]*u[b,h,L-1],  kk[h,l] = k[h, L-1-l]
// u = relu(data@w1+b1)@w2 + b2   (fused, never materialized)
//
// Ledger: best = 129.9 (R19: atomic-P epilogue + k_mid/k_fin tail + prep
//   tweaks). Prior best 134.6 (R2). R18 lesson (re-read): old k_tail was
//   VGPR-SPILL bound (VGPR=64 @1024thr, 3.3MB scratch writes/rep) -- fixed
//   by k_mid/k_fin split. T_prep ~37us vs 3-5us model: UNRESOLVED 10x gap.
// R20 (2nd resubmit -- R11/R12 benches were GPU-acquisition timeouts):
//   INSTRUMENTATION -- rep<3 on k_prep ONLY (k_main/k_mid/k_fin frozen
//   at R19-best). total = 129.9 + 2*T_prep; k_prep lands in top-5 with
//   VGPR/VALUBusy/WRITE counters to pick between spill / slow-transcendental
//   / straggler theories. REVERT rep=1 NEXT ROUND and apply the indicated fix.

#define L_LEN 4096
#define H_DIM 256
#define J_DIM 128
#define DIN   32
#define NSTATE 32

typedef float f32x4 __attribute__((ext_vector_type(4)));
typedef short s16x8 __attribute__((ext_vector_type(8)));

__device__ __forceinline__ short f2bf(float x) {
  union { float f; unsigned u; } a; a.f = x;
  unsigned r = a.u + 0x7fffu + ((a.u >> 16) & 1u);  // RNE
  return (short)(r >> 16);
}

// ============ kernel 1: prep (w1T/w2T bf16, kkP permuted, P zeroed) ==========
// R20: body wrapped in rep<3 (idempotent) for instrumentation -- REVERT NEXT.
__global__ __launch_bounds__(256) void k_prep(
    const float* __restrict__ w1, const float* __restrict__ w2,
    const float* __restrict__ log_dt,
    const float* __restrict__ A_re, const float* __restrict__ A_im,
    const float* __restrict__ C_re, const float* __restrict__ C_im,
    float* __restrict__ kkP,
    short* __restrict__ w1T, short* __restrict__ w2T,
    float* __restrict__ P)
{
  const int bid = blockIdx.x, tid = threadIdx.x;
  __shared__ float kcr[512], kci[512];   // Kc for this block's 16-h group

#pragma unroll 1
  for (int rep = 0; rep < 3; ++rep) {    // R20 instrumentation loop

  // ---- elementwise prep + P zero-init: first 176 blocks cover 45056 items --
  {
    int i = bid * 256 + tid;
    if (i < 4096) {
      int n = i >> 5, k = i & 31;        // w1T[n][k] bf16, w1 is (32,128)
      w1T[i] = f2bf(w1[k * J_DIM + n]);
    } else if (i < 36864) {
      int idx = i - 4096;                // w2T[h][k] bf16, w2 is (128,256)
      int h = idx >> 7, k = idx & 127;
      w2T[idx] = f2bf(w2[k * H_DIM + h]);
    } else if (i < 45056) {
      P[i - 36864] = 0.f;                // P (32x256) for k_main atomics
    }
  }

  // ---- Kc for this h-group (computed once; reused for 4 lc-chunks) ----
  const int hg = bid >> 6, lcg = bid & 63;
  for (int e = tid; e < 512; e += 256) {
    int n = e & 31, h2 = e >> 5;
    int h = hg * 16 + h2;
    float dt = __expf(log_dt[h]);
    float are = A_re[h * NSTATE + n], aim = A_im[h * NSTATE + n];
    float dr = dt * are, di = dt * aim;
    float ed = __expf(dr);
    float c = __cosf(di), s = __sinf(di);
    float nr = ed * c - 1.f, ni = ed * s;
    float d2 = are * are + aim * aim;
    float qr = (nr * are + ni * aim) / d2;
    float qi = (ni * are - nr * aim) / d2;
    float cr = C_re[h * NSTATE + n], ci = C_im[h * NSTATE + n];
    kcr[n * 16 + h2] = cr * qr - ci * qi;
    kci[n * 16 + h2] = cr * qi + ci * qr;
  }
  __syncthreads();

  // ---- kk(h, L-1-l) for 4 16x16 (l,h) tiles; write permuted ----
  {
    const int hh = tid & 15, lw = tid >> 4;
    const int h = hg * 16 + hh;
    const float dt = __expf(log_dt[h]);
    const float ar  = A_re[h * NSTATE];
    const float aib = A_im[h * NSTATE + 1];

    // register-cache this thread's Kc column (64 ds_reads total, reused 4x)
    float kr[32], ki[32];
#pragma unroll
    for (int n = 0; n < NSTATE; n++) {
      kr[n] = kcr[n * 16 + hh];
      ki[n] = kci[n * 16 + hh];
    }

#pragma unroll
    for (int it = 0; it < 4; it++) {
      int lc = lcg * 4 + it;
      int l = lc * 16 + lw;
      float fm = (float)((L_LEN - 1) - l);
      float mag = __expf(dt * ar * fm);
      float th = dt * aib * fm;
      float s1 = __sinf(th), c1 = __cosf(th);
      float cn = 1.f, sn = 0.f, acc = 0.f;
#pragma unroll
      for (int n = 0; n < NSTATE; n++) {
        acc += kr[n] * cn - ki[n] * sn;
        float c2 = cn * c1 - sn * s1;
        sn = sn * c1 + cn * s1;
        cn = c2;
      }
      float val = 2.f * mag * acc;
      int c  = l >> 6, rt = (l >> 4) & 3, q = (l >> 2) & 3, r = l & 3;
      int w  = h >> 6, ht = (h >> 4) & 3, s15 = h & 15;
      kkP[((((c * 4 + w) * 4 + ht) * 4 + rt) * 64 + q * 16 + s15) * 4 + r] = val;
    }
  }

  __syncthreads();                       // WAR guard before next rep
  }                                      // end rep
}

// ============ kernel 2: fused MLP + weighted reduce, 2 batches/block =========
// R11-proven structure. 1024 blocks: l0 = (bidx&63)*64, bp = bidx>>6.
// R19: epilogue atomicAdds partials into P[b,h] (P zeroed by k_prep).
__global__ __launch_bounds__(256) void k_main(
    const float* __restrict__ data, const float* __restrict__ b1v,
    const float* __restrict__ b2v, const float* __restrict__ Dv,
    const short* __restrict__ w1T, const short* __restrict__ w2T,
    const float* __restrict__ kkP, float* __restrict__ P)
{
  const int bidx = blockIdx.x, tid = threadIdx.x;
  const int wave = tid >> 6, lane = tid & 63;
  const int quad = lane >> 4, l15 = lane & 15;
  const int bp = bidx >> 6;              // batch pair
  const int lc = bidx & 63;
  const int l0 = lc * 64;

  __shared__ short x1s[2][64 * 136];     // two bf16 x1 tiles (one per batch)

  // ---- Phase A: x1 = relu(data_tile @ w1 + b1) -> LDS, both batches ----
#pragma unroll
  for (int bb = 0; bb < 2; bb++) {
    const int b = bp * 2 + bb;
    const float* dp = data + ((size_t)b * L_LEN + (size_t)(l0 + wave * 16 + l15)) * DIN + quad * 8;
    f32x4 d0 = *(const f32x4*)dp;
    f32x4 d1 = *(const f32x4*)(dp + 4);
    s16x8 af;
    af[0] = f2bf(d0[0]); af[1] = f2bf(d0[1]); af[2] = f2bf(d0[2]); af[3] = f2bf(d0[3]);
    af[4] = f2bf(d1[0]); af[5] = f2bf(d1[1]); af[6] = f2bf(d1[2]); af[7] = f2bf(d1[3]);
#pragma unroll
    for (int c = 0; c < 8; c++) {
      s16x8 bf = *(const s16x8*)(w1T + (c * 16 + l15) * DIN + quad * 8);
      f32x4 a0 = {0.f, 0.f, 0.f, 0.f};
      a0 = __builtin_amdgcn_mfma_f32_16x16x32_bf16(af, bf, a0, 0, 0, 0);
      float bbi = b1v[c * 16 + l15];
#pragma unroll
      for (int r = 0; r < 4; r++) {
        float v = fmaxf(a0[r] + bbi, 0.f);
        x1s[bb][(wave * 16 + quad * 4 + r) * 136 + c * 16 + l15] = f2bf(v);
      }
    }
  }

  // ---- w2 B-fragments in registers (loaded once, reused for both batches) ----
  s16x8 wf[4][4];
#pragma unroll
  for (int ht = 0; ht < 4; ht++)
#pragma unroll
    for (int ks = 0; ks < 4; ks++)
      wf[ht][ks] = *(const s16x8*)(w2T + (wave * 64 + ht * 16 + l15) * J_DIM + ks * 32 + quad * 8);

  __syncthreads();

#pragma unroll 1
  for (int bb = 0; bb < 2; bb++) {
    const int b = bp * 2 + bb;

    f32x4 acc[4][4];
#pragma unroll
    for (int rt = 0; rt < 4; rt++)
#pragma unroll
      for (int ht = 0; ht < 4; ht++)
        acc[rt][ht] = (f32x4){0.f, 0.f, 0.f, 0.f};

    // ---- Phase B: u-tile = x1 @ w2 (64 MFMAs/wave) ----
#pragma unroll
    for (int ks = 0; ks < 4; ks++) {
#pragma unroll
      for (int rt = 0; rt < 4; rt++) {
        s16x8 af = *(const s16x8*)&x1s[bb][(rt * 16 + l15) * 136 + ks * 32 + quad * 8];
#pragma unroll
        for (int ht = 0; ht < 4; ht++)
          acc[rt][ht] = __builtin_amdgcn_mfma_f32_16x16x32_bf16(af, wf[ht][ks], acc[rt][ht], 0, 0, 0);
      }
    }

    // ---- Epilogue: P[b,h] += sum_rows kk*(u+b2) (+ D at l=L-1) ----
#pragma unroll
    for (int ht = 0; ht < 4; ht++) {
      int h = wave * 64 + ht * 16 + l15;   // C-layout: col = lane&15
      float b2h = b2v[h], Dh = Dv[h];
      const f32x4* kp = ((const f32x4*)kkP)
                      + (((lc * 4 + wave) * 4 + ht) * 4) * 64 + lane;
      float s = 0.f;
#pragma unroll
      for (int rt = 0; rt < 4; rt++) {
        f32x4 kv = kp[rt * 64];
#pragma unroll
        for (int r = 0; r < 4; r++) {
          int l = l0 + rt * 16 + quad * 4 + r;   // C-layout: row = quad*4+reg
          float uu = acc[rt][ht][r] + b2h;
          s = fmaf(kv[r], uu, s);
          if (l == L_LEN - 1) s = fmaf(Dh, uu, s);
        }
      }
      s += __shfl_xor(s, 16, 64);
      s += __shfl_xor(s, 32, 64);
      if (quad == 0) atomicAdd(&P[(size_t)b * H_DIM + h], s);
    }
  }
}

// ============ kernel 3a: gelu(P) @ Wg + bg -> GLU -> glu (32x256) ============
// 256 blocks x 1024: block = (b, cg); cg covers a-cols cg*32..+32 and their
// b-col partners +256. 16-way K-split: 16 independent loads/thread.
__global__ __launch_bounds__(1024) void k_mid(
    const float* __restrict__ P, const float* __restrict__ Wg,
    const float* __restrict__ bgv, float* __restrict__ glu)
{
  const int bid = blockIdx.x, t = threadIdx.x;
  const int b = bid >> 3, cg = bid & 7;
  __shared__ float gs[H_DIM];
  __shared__ float part[16][64];
  __shared__ float yy[64];

  if (t < H_DIM) {
    float p = P[b * H_DIM + t];
    gs[t] = 0.5f * p * (1.f + erff(p * 0.70710678118654752f));  // exact gelu
  }
  __syncthreads();

  {
    int ci = t & 63, kc = t >> 6;        // 16 ksplit x 16 j each
    int col = (ci < 32) ? (cg * 32 + ci) : (256 + cg * 32 + (ci - 32));
    float acc = 0.f;
#pragma unroll
    for (int jj = 0; jj < 16; jj++) {
      int j = kc * 16 + jj;
      acc = fmaf(gs[j], Wg[(size_t)j * 512 + col], acc);
    }
    part[kc][ci] = acc;
  }
  __syncthreads();

  if (t < 64) {
    int col = (t < 32) ? (cg * 32 + t) : (256 + cg * 32 + (t - 32));
    float s = bgv[col];
#pragma unroll
    for (int k2 = 0; k2 < 16; k2++) s += part[k2][t];
    yy[t] = s;
  }
  __syncthreads();

  if (t < 32) {
    float a = yy[t], bb = yy[t + 32];
    glu[b * H_DIM + cg * 32 + t] = a * (1.f / (1.f + __expf(-bb)));
  }
}

// ============ kernel 3b: z = relu(glu@w3+b3); out = z@w4+b4 ==================
__global__ __launch_bounds__(1024) void k_fin(
    const float* __restrict__ glu, const float* __restrict__ w3,
    const float* __restrict__ b3v, const float* __restrict__ w4,
    const float* __restrict__ b4v, float* __restrict__ out)
{
  const int b = blockIdx.x, t = threadIdx.x;
  __shared__ float gl[H_DIM];
  __shared__ float zp[8][J_DIM];
  __shared__ float zf[J_DIM];

  if (t < H_DIM) gl[t] = glu[b * H_DIM + t];
  __syncthreads();

  // z = relu(gl @ w3 + b3): 128 cols x 8-way K-split (32 each)
  {
    int col = t & 127, kc = t >> 7;
    const float* wp = w3 + (size_t)(kc * 32) * J_DIM + col;
    float acc = 0.f;
#pragma unroll
    for (int j = 0; j < 32; j++)
      acc = fmaf(gl[kc * 32 + j], wp[(size_t)j * J_DIM], acc);
    zp[kc][col] = acc;
  }
  __syncthreads();
  if (t < J_DIM) {
    float s = b3v[t];
#pragma unroll
    for (int k = 0; k < 8; k++) s += zp[k][t];
    zf[t] = fmaxf(s, 0.f);
  }
  __syncthreads();

  if (t < 16) {
    float s = b4v[t];
#pragma unroll
    for (int i = 0; i < J_DIM; i++)
      s = fmaf(zf[i], w4[i * 16 + t], s);
    out[b * 16 + t] = s;
  }
}

extern "C" void kernel_launch(void* const* d_in, const int* in_sizes, int n_in,
                              void* d_out, int out_size, void* d_ws, size_t ws_size,
                              hipStream_t stream)
{
  const float* data   = (const float*)d_in[0];
  const float* w1     = (const float*)d_in[1];
  const float* b1v    = (const float*)d_in[2];
  const float* w2     = (const float*)d_in[3];
  const float* b2v    = (const float*)d_in[4];
  const float* log_dt = (const float*)d_in[5];
  const float* A_re   = (const float*)d_in[6];
  const float* A_im   = (const float*)d_in[7];
  const float* C_re   = (const float*)d_in[8];
  const float* C_im   = (const float*)d_in[9];
  const float* Dv     = (const float*)d_in[10];
  const float* Wg     = (const float*)d_in[11];
  const float* bgv    = (const float*)d_in[12];
  const float* w3     = (const float*)d_in[13];
  const float* b3v    = (const float*)d_in[14];
  const float* w4     = (const float*)d_in[15];
  const float* b4v    = (const float*)d_in[16];
  float* outp = (float*)d_out;

  // workspace layout (~4.4 MB)
  char* ws = (char*)d_ws;
  float* kkP = (float*)ws;                    // 4 MB (permuted kk)
  float* P   = (float*)(ws + 4194304);        // 32 KB (32 x 256, atomics)
  float* glu = (float*)(ws + 4227072);        // 32 KB (32 x 256)
  short* w1T = (short*)(ws + 4259840);        // 8 KB
  short* w2T = (short*)(ws + 4268032);        // 64 KB

  k_prep<<<1024, 256, 0, stream>>>(w1, w2, log_dt, A_re, A_im, C_re, C_im,
                                   kkP, w1T, w2T, P);
  k_main<<<1024, 256, 0, stream>>>(data, b1v, b2v, Dv, w1T, w2T, kkP, P);
  k_mid<<<256, 1024, 0, stream>>>(P, Wg, bgv, glu);
  k_fin<<<32, 1024, 0, stream>>>(glu, w3, b3v, w4, b4v, outp);
}

// Round 15
// 143.411 us; speedup vs baseline: 1.0790x; 1.0790x over previous
//
#include <hip/hip_runtime.h>
#include <math.h>

// S4 forward, collapsed: out depends only on conv output at t = L-1.
// P[b,h] = sum_l kk[h,l]*u[b,h,l] + D[h]*u[b,h,L-1],  kk[h,l] = k[h, L-1-l]
// u = relu(data@w1+b1)@w2 + b2   (fused, never materialized)
//
// Ledger: best = 129.9 (R19). Budget (R17/R18/R20 instrumentation):
//   fill+fixed ~43, gaps ~24, prep ~12.4, main ~21 (VGPR=148 -> 3 waves/SIMD),
//   mid+fin ~20. Rejected: hp-split, forced-occ (NEVER bound below natural
//   VGPR), hoist+prefetch+pad, no-LDS waves, tail-split-v1.
// R21 (resubmit -- R14 bench was a GPU-acquisition timeout, never ran):
//   k_main register diet WITHOUT bounds -- wf[4][4] (64 VGPR persistent)
//   replaced by per-ks wk[4] loads inside a '#pragma unroll 1' ks-loop (real
//   loop = compiler can't hoist all 16 frags). Peak live ~120 -> target
//   VGPR<=128 = 4 waves/SIMD (m69 halving boundary). Everything else frozen.

#define L_LEN 4096
#define H_DIM 256
#define J_DIM 128
#define DIN   32
#define NSTATE 32

typedef float f32x4 __attribute__((ext_vector_type(4)));
typedef short s16x8 __attribute__((ext_vector_type(8)));

__device__ __forceinline__ short f2bf(float x) {
  union { float f; unsigned u; } a; a.f = x;
  unsigned r = a.u + 0x7fffu + ((a.u >> 16) & 1u);  // RNE
  return (short)(r >> 16);
}

// ============ kernel 1: prep (w1T/w2T bf16, kkP permuted, P zeroed) ==========
// R19-proven (T_prep ~12.4us). 1024 blocks: hg = bid>>6, lcg = bid&63.
// kkP layout (floats): idx = ((((c*4+w)*4+ht)*4+rt)*64 + q*16+s15)*4 + r
//   where l = c*64+rt*16+q*4+r, h = w*64+ht*16+s15 -- MFMA C-fragment order.
__global__ __launch_bounds__(256) void k_prep(
    const float* __restrict__ w1, const float* __restrict__ w2,
    const float* __restrict__ log_dt,
    const float* __restrict__ A_re, const float* __restrict__ A_im,
    const float* __restrict__ C_re, const float* __restrict__ C_im,
    float* __restrict__ kkP,
    short* __restrict__ w1T, short* __restrict__ w2T,
    float* __restrict__ P)
{
  const int bid = blockIdx.x, tid = threadIdx.x;
  __shared__ float kcr[512], kci[512];   // Kc for this block's 16-h group

  // ---- elementwise prep + P zero-init: first 176 blocks cover 45056 items --
  {
    int i = bid * 256 + tid;
    if (i < 4096) {
      int n = i >> 5, k = i & 31;        // w1T[n][k] bf16, w1 is (32,128)
      w1T[i] = f2bf(w1[k * J_DIM + n]);
    } else if (i < 36864) {
      int idx = i - 4096;                // w2T[h][k] bf16, w2 is (128,256)
      int h = idx >> 7, k = idx & 127;
      w2T[idx] = f2bf(w2[k * H_DIM + h]);
    } else if (i < 45056) {
      P[i - 36864] = 0.f;                // P (32x256) for k_main atomics
    }
  }

  // ---- Kc for this h-group (computed once; reused for 4 lc-chunks) ----
  const int hg = bid >> 6, lcg = bid & 63;
  for (int e = tid; e < 512; e += 256) {
    int n = e & 31, h2 = e >> 5;
    int h = hg * 16 + h2;
    float dt = __expf(log_dt[h]);
    float are = A_re[h * NSTATE + n], aim = A_im[h * NSTATE + n];
    float dr = dt * are, di = dt * aim;
    float ed = __expf(dr);
    float c = __cosf(di), s = __sinf(di);
    float nr = ed * c - 1.f, ni = ed * s;
    float d2 = are * are + aim * aim;
    float qr = (nr * are + ni * aim) / d2;
    float qi = (ni * are - nr * aim) / d2;
    float cr = C_re[h * NSTATE + n], ci = C_im[h * NSTATE + n];
    kcr[n * 16 + h2] = cr * qr - ci * qi;
    kci[n * 16 + h2] = cr * qi + ci * qr;
  }
  __syncthreads();

  // ---- kk(h, L-1-l) for 4 16x16 (l,h) tiles; write permuted ----
  const int hh = tid & 15, lw = tid >> 4;
  const int h = hg * 16 + hh;
  const float dt = __expf(log_dt[h]);
  const float ar  = A_re[h * NSTATE];
  const float aib = A_im[h * NSTATE + 1];

  // register-cache this thread's Kc column (64 ds_reads total, reused 4x)
  float kr[32], ki[32];
#pragma unroll
  for (int n = 0; n < NSTATE; n++) {
    kr[n] = kcr[n * 16 + hh];
    ki[n] = kci[n * 16 + hh];
  }

#pragma unroll
  for (int it = 0; it < 4; it++) {
    int lc = lcg * 4 + it;
    int l = lc * 16 + lw;
    float fm = (float)((L_LEN - 1) - l);
    float mag = __expf(dt * ar * fm);
    float th = dt * aib * fm;
    float s1 = __sinf(th), c1 = __cosf(th);
    float cn = 1.f, sn = 0.f, acc = 0.f;
#pragma unroll
    for (int n = 0; n < NSTATE; n++) {
      acc += kr[n] * cn - ki[n] * sn;
      float c2 = cn * c1 - sn * s1;
      sn = sn * c1 + cn * s1;
      cn = c2;
    }
    float val = 2.f * mag * acc;
    int c  = l >> 6, rt = (l >> 4) & 3, q = (l >> 2) & 3, r = l & 3;
    int w  = h >> 6, ht = (h >> 4) & 3, s15 = h & 15;
    kkP[((((c * 4 + w) * 4 + ht) * 4 + rt) * 64 + q * 16 + s15) * 4 + r] = val;
  }
}

// ============ kernel 2: fused MLP + weighted reduce, 2 batches/block =========
// 1024 blocks: l0 = (bidx&63)*64, bp = bidx>>6. Atomic-P epilogue (R19).
// R21: per-ks wk loads in an unroll-1 ks-loop (register diet, no bound).
__global__ __launch_bounds__(256) void k_main(
    const float* __restrict__ data, const float* __restrict__ b1v,
    const float* __restrict__ b2v, const float* __restrict__ Dv,
    const short* __restrict__ w1T, const short* __restrict__ w2T,
    const float* __restrict__ kkP, float* __restrict__ P)
{
  const int bidx = blockIdx.x, tid = threadIdx.x;
  const int wave = tid >> 6, lane = tid & 63;
  const int quad = lane >> 4, l15 = lane & 15;
  const int bp = bidx >> 6;              // batch pair
  const int lc = bidx & 63;
  const int l0 = lc * 64;

  __shared__ short x1s[2][64 * 136];     // two bf16 x1 tiles (one per batch)

  // ---- Phase A: x1 = relu(data_tile @ w1 + b1) -> LDS, both batches ----
#pragma unroll
  for (int bb = 0; bb < 2; bb++) {
    const int b = bp * 2 + bb;
    const float* dp = data + ((size_t)b * L_LEN + (size_t)(l0 + wave * 16 + l15)) * DIN + quad * 8;
    f32x4 d0 = *(const f32x4*)dp;
    f32x4 d1 = *(const f32x4*)(dp + 4);
    s16x8 af;
    af[0] = f2bf(d0[0]); af[1] = f2bf(d0[1]); af[2] = f2bf(d0[2]); af[3] = f2bf(d0[3]);
    af[4] = f2bf(d1[0]); af[5] = f2bf(d1[1]); af[6] = f2bf(d1[2]); af[7] = f2bf(d1[3]);
#pragma unroll
    for (int c = 0; c < 8; c++) {
      s16x8 bf = *(const s16x8*)(w1T + (c * 16 + l15) * DIN + quad * 8);
      f32x4 a0 = {0.f, 0.f, 0.f, 0.f};
      a0 = __builtin_amdgcn_mfma_f32_16x16x32_bf16(af, bf, a0, 0, 0, 0);
      float bbi = b1v[c * 16 + l15];
#pragma unroll
      for (int r = 0; r < 4; r++) {
        float v = fmaxf(a0[r] + bbi, 0.f);
        x1s[bb][(wave * 16 + quad * 4 + r) * 136 + c * 16 + l15] = f2bf(v);
      }
    }
  }

  __syncthreads();

#pragma unroll 1
  for (int bb = 0; bb < 2; bb++) {
    const int b = bp * 2 + bb;

    f32x4 acc[4][4];
#pragma unroll
    for (int rt = 0; rt < 4; rt++)
#pragma unroll
      for (int ht = 0; ht < 4; ht++)
        acc[rt][ht] = (f32x4){0.f, 0.f, 0.f, 0.f};

    // ---- Phase B: u-tile = x1 @ w2 (64 MFMAs/wave); wk per-ks, unroll 1
    //      keeps only 16 weight VGPRs live (vs 64 persistent) ----
#pragma unroll 1
    for (int ks = 0; ks < 4; ks++) {
      s16x8 wk[4];
#pragma unroll
      for (int ht = 0; ht < 4; ht++)
        wk[ht] = *(const s16x8*)(w2T + (wave * 64 + ht * 16 + l15) * J_DIM + ks * 32 + quad * 8);
#pragma unroll
      for (int rt = 0; rt < 4; rt++) {
        s16x8 af = *(const s16x8*)&x1s[bb][(rt * 16 + l15) * 136 + ks * 32 + quad * 8];
#pragma unroll
        for (int ht = 0; ht < 4; ht++)
          acc[rt][ht] = __builtin_amdgcn_mfma_f32_16x16x32_bf16(af, wk[ht], acc[rt][ht], 0, 0, 0);
      }
    }

    // ---- Epilogue: P[b,h] += sum_rows kk*(u+b2) (+ D at l=L-1) ----
#pragma unroll
    for (int ht = 0; ht < 4; ht++) {
      int h = wave * 64 + ht * 16 + l15;   // C-layout: col = lane&15
      float b2h = b2v[h], Dh = Dv[h];
      const f32x4* kp = ((const f32x4*)kkP)
                      + (((lc * 4 + wave) * 4 + ht) * 4) * 64 + lane;
      float s = 0.f;
#pragma unroll
      for (int rt = 0; rt < 4; rt++) {
        f32x4 kv = kp[rt * 64];
#pragma unroll
        for (int r = 0; r < 4; r++) {
          int l = l0 + rt * 16 + quad * 4 + r;   // C-layout: row = quad*4+reg
          float uu = acc[rt][ht][r] + b2h;
          s = fmaf(kv[r], uu, s);
          if (l == L_LEN - 1) s = fmaf(Dh, uu, s);
        }
      }
      s += __shfl_xor(s, 16, 64);
      s += __shfl_xor(s, 32, 64);
      if (quad == 0) atomicAdd(&P[(size_t)b * H_DIM + h], s);
    }
  }
}

// ============ kernel 3a: gelu(P) @ Wg + bg -> GLU -> glu (32x256) ============
// 256 blocks x 1024: block = (b, cg); cg covers a-cols cg*32..+32 and their
// b-col partners +256. 16-way K-split: 16 independent loads/thread.
__global__ __launch_bounds__(1024) void k_mid(
    const float* __restrict__ P, const float* __restrict__ Wg,
    const float* __restrict__ bgv, float* __restrict__ glu)
{
  const int bid = blockIdx.x, t = threadIdx.x;
  const int b = bid >> 3, cg = bid & 7;
  __shared__ float gs[H_DIM];
  __shared__ float part[16][64];
  __shared__ float yy[64];

  if (t < H_DIM) {
    float p = P[b * H_DIM + t];
    gs[t] = 0.5f * p * (1.f + erff(p * 0.70710678118654752f));  // exact gelu
  }
  __syncthreads();

  {
    int ci = t & 63, kc = t >> 6;        // 16 ksplit x 16 j each
    int col = (ci < 32) ? (cg * 32 + ci) : (256 + cg * 32 + (ci - 32));
    float acc = 0.f;
#pragma unroll
    for (int jj = 0; jj < 16; jj++) {
      int j = kc * 16 + jj;
      acc = fmaf(gs[j], Wg[(size_t)j * 512 + col], acc);
    }
    part[kc][ci] = acc;
  }
  __syncthreads();

  if (t < 64) {
    int col = (t < 32) ? (cg * 32 + t) : (256 + cg * 32 + (t - 32));
    float s = bgv[col];
#pragma unroll
    for (int k2 = 0; k2 < 16; k2++) s += part[k2][t];
    yy[t] = s;
  }
  __syncthreads();

  if (t < 32) {
    float a = yy[t], bb = yy[t + 32];
    glu[b * H_DIM + cg * 32 + t] = a * (1.f / (1.f + __expf(-bb)));
  }
}

// ============ kernel 3b: z = relu(glu@w3+b3); out = z@w4+b4 ==================
__global__ __launch_bounds__(1024) void k_fin(
    const float* __restrict__ glu, const float* __restrict__ w3,
    const float* __restrict__ b3v, const float* __restrict__ w4,
    const float* __restrict__ b4v, float* __restrict__ out)
{
  const int b = blockIdx.x, t = threadIdx.x;
  __shared__ float gl[H_DIM];
  __shared__ float zp[8][J_DIM];
  __shared__ float zf[J_DIM];

  if (t < H_DIM) gl[t] = glu[b * H_DIM + t];
  __syncthreads();

  // z = relu(gl @ w3 + b3): 128 cols x 8-way K-split (32 each)
  {
    int col = t & 127, kc = t >> 7;
    const float* wp = w3 + (size_t)(kc * 32) * J_DIM + col;
    float acc = 0.f;
#pragma unroll
    for (int j = 0; j < 32; j++)
      acc = fmaf(gl[kc * 32 + j], wp[(size_t)j * J_DIM], acc);
    zp[kc][col] = acc;
  }
  __syncthreads();
  if (t < J_DIM) {
    float s = b3v[t];
#pragma unroll
    for (int k = 0; k < 8; k++) s += zp[k][t];
    zf[t] = fmaxf(s, 0.f);
  }
  __syncthreads();

  if (t < 16) {
    float s = b4v[t];
#pragma unroll
    for (int i = 0; i < J_DIM; i++)
      s = fmaf(zf[i], w4[i * 16 + t], s);
    out[b * 16 + t] = s;
  }
}

extern "C" void kernel_launch(void* const* d_in, const int* in_sizes, int n_in,
                              void* d_out, int out_size, void* d_ws, size_t ws_size,
                              hipStream_t stream)
{
  const float* data   = (const float*)d_in[0];
  const float* w1     = (const float*)d_in[1];
  const float* b1v    = (const float*)d_in[2];
  const float* w2     = (const float*)d_in[3];
  const float* b2v    = (const float*)d_in[4];
  const float* log_dt = (const float*)d_in[5];
  const float* A_re   = (const float*)d_in[6];
  const float* A_im   = (const float*)d_in[7];
  const float* C_re   = (const float*)d_in[8];
  const float* C_im   = (const float*)d_in[9];
  const float* Dv     = (const float*)d_in[10];
  const float* Wg     = (const float*)d_in[11];
  const float* bgv    = (const float*)d_in[12];
  const float* w3     = (const float*)d_in[13];
  const float* b3v    = (const float*)d_in[14];
  const float* w4     = (const float*)d_in[15];
  const float* b4v    = (const float*)d_in[16];
  float* outp = (float*)d_out;

  // workspace layout (~4.4 MB)
  char* ws = (char*)d_ws;
  float* kkP = (float*)ws;                    // 4 MB (permuted kk)
  float* P   = (float*)(ws + 4194304);        // 32 KB (32 x 256, atomics)
  float* glu = (float*)(ws + 4227072);        // 32 KB (32 x 256)
  short* w1T = (short*)(ws + 4259840);        // 8 KB
  short* w2T = (short*)(ws + 4268032);        // 64 KB

  k_prep<<<1024, 256, 0, stream>>>(w1, w2, log_dt, A_re, A_im, C_re, C_im,
                                   kkP, w1T, w2T, P);
  k_main<<<1024, 256, 0, stream>>>(data, b1v, b2v, Dv, w1T, w2T, kkP, P);
  k_mid<<<256, 1024, 0, stream>>>(P, Wg, bgv, glu);
  k_fin<<<32, 1024, 0, stream>>>(glu, w3, b3v, w4, b4v, outp);
}

// Round 16
// 129.294 us; speedup vs baseline: 1.1968x; 1.1092x over previous
//
#include <hip/hip_runtime.h>
#include <math.h>

// S4 forward, collapsed: out depends only on conv output at t = L-1.
// P[b,h] = sum_l kk[h,l]*u[b,h,l] + D[h]*u[b,h,L-1],  kk[h,l] = k[h, L-1-l]
// u = relu(data@w1+b1)@w2 + b2   (fused, never materialized)
//
// FINAL CONFIG = R19 (measured 129.9us, Round 11). Ledger:
//   R2 134.6 -> R19 129.9 via: atomic-P epilogue (kills 64-way Pp reduce),
//   k_mid/k_fin tail split (fixes k_tail VGPR-spill, VALUBusy was 0.73%),
//   register-Kc + __sinf/__cosf prep (37->12.4us).
// Rejected across session: hp-split (146.4), forced-occ bound (176.6, spill),
//   hoist+prefetch+pad bundle (138.5), no-LDS wave-indep (153.8),
//   tail-split-v1 (147.0), 2048-blk (140.1), unroll-1 wk diet (143.4:
//   VGPR only 148->132, still 3 waves/SIMD, Phase B serialized).
// Budget (R17/R18/R20 rep-loop instrumentation): fill+fixed ~43, gaps ~24,
//   prep ~12.4, main ~21 (issue/latency-bound, all pipes <26%), mid+fin ~20.
// Conclusion: every controllable kernel within ~2x of latency floor; residual
//   dominated by harness fill + dispatch overhead. This is the keeper.

#define L_LEN 4096
#define H_DIM 256
#define J_DIM 128
#define DIN   32
#define NSTATE 32

typedef float f32x4 __attribute__((ext_vector_type(4)));
typedef short s16x8 __attribute__((ext_vector_type(8)));

__device__ __forceinline__ short f2bf(float x) {
  union { float f; unsigned u; } a; a.f = x;
  unsigned r = a.u + 0x7fffu + ((a.u >> 16) & 1u);  // RNE
  return (short)(r >> 16);
}

// ============ kernel 1: prep (w1T/w2T bf16, kkP permuted, P zeroed) ==========
// 1024 blocks: hg = bid>>6 (16 h-groups), lcg = bid&63; each block does
// lc = lcg*4 .. lcg*4+3 (4 l-chunks) with ONE Kc computation.
// kkP layout (floats): idx = ((((c*4+w)*4+ht)*4+rt)*64 + q*16+s15)*4 + r
//   where l = c*64+rt*16+q*4+r, h = w*64+ht*16+s15 -- MFMA C-fragment order.
__global__ __launch_bounds__(256) void k_prep(
    const float* __restrict__ w1, const float* __restrict__ w2,
    const float* __restrict__ log_dt,
    const float* __restrict__ A_re, const float* __restrict__ A_im,
    const float* __restrict__ C_re, const float* __restrict__ C_im,
    float* __restrict__ kkP,
    short* __restrict__ w1T, short* __restrict__ w2T,
    float* __restrict__ P)
{
  const int bid = blockIdx.x, tid = threadIdx.x;
  __shared__ float kcr[512], kci[512];   // Kc for this block's 16-h group

  // ---- elementwise prep + P zero-init: first 176 blocks cover 45056 items --
  {
    int i = bid * 256 + tid;
    if (i < 4096) {
      int n = i >> 5, k = i & 31;        // w1T[n][k] bf16, w1 is (32,128)
      w1T[i] = f2bf(w1[k * J_DIM + n]);
    } else if (i < 36864) {
      int idx = i - 4096;                // w2T[h][k] bf16, w2 is (128,256)
      int h = idx >> 7, k = idx & 127;
      w2T[idx] = f2bf(w2[k * H_DIM + h]);
    } else if (i < 45056) {
      P[i - 36864] = 0.f;                // P (32x256) for k_main atomics
    }
  }

  // ---- Kc for this h-group (computed once; reused for 4 lc-chunks) ----
  const int hg = bid >> 6, lcg = bid & 63;
  for (int e = tid; e < 512; e += 256) {
    int n = e & 31, h2 = e >> 5;
    int h = hg * 16 + h2;
    float dt = __expf(log_dt[h]);
    float are = A_re[h * NSTATE + n], aim = A_im[h * NSTATE + n];
    float dr = dt * are, di = dt * aim;
    float ed = __expf(dr);
    float c = __cosf(di), s = __sinf(di);
    float nr = ed * c - 1.f, ni = ed * s;
    float d2 = are * are + aim * aim;
    float qr = (nr * are + ni * aim) / d2;
    float qi = (ni * are - nr * aim) / d2;
    float cr = C_re[h * NSTATE + n], ci = C_im[h * NSTATE + n];
    kcr[n * 16 + h2] = cr * qr - ci * qi;
    kci[n * 16 + h2] = cr * qi + ci * qr;
  }
  __syncthreads();

  // ---- kk(h, L-1-l) for 4 16x16 (l,h) tiles; write permuted ----
  const int hh = tid & 15, lw = tid >> 4;
  const int h = hg * 16 + hh;
  const float dt = __expf(log_dt[h]);
  const float ar  = A_re[h * NSTATE];
  const float aib = A_im[h * NSTATE + 1];

  // register-cache this thread's Kc column (64 ds_reads total, reused 4x)
  float kr[32], ki[32];
#pragma unroll
  for (int n = 0; n < NSTATE; n++) {
    kr[n] = kcr[n * 16 + hh];
    ki[n] = kci[n * 16 + hh];
  }

#pragma unroll
  for (int it = 0; it < 4; it++) {
    int lc = lcg * 4 + it;
    int l = lc * 16 + lw;
    float fm = (float)((L_LEN - 1) - l);
    float mag = __expf(dt * ar * fm);
    float th = dt * aib * fm;
    float s1 = __sinf(th), c1 = __cosf(th);
    float cn = 1.f, sn = 0.f, acc = 0.f;
#pragma unroll
    for (int n = 0; n < NSTATE; n++) {
      acc += kr[n] * cn - ki[n] * sn;
      float c2 = cn * c1 - sn * s1;
      sn = sn * c1 + cn * s1;
      cn = c2;
    }
    float val = 2.f * mag * acc;
    int c  = l >> 6, rt = (l >> 4) & 3, q = (l >> 2) & 3, r = l & 3;
    int w  = h >> 6, ht = (h >> 4) & 3, s15 = h & 15;
    kkP[((((c * 4 + w) * 4 + ht) * 4 + rt) * 64 + q * 16 + s15) * 4 + r] = val;
  }
}

// ============ kernel 2: fused MLP + weighted reduce, 2 batches/block =========
// R11-proven structure. 1024 blocks: l0 = (bidx&63)*64, bp = bidx>>6.
// Persistent wf[4][4] (VGPR=148, 3 waves/SIMD -- proven optimum).
// Epilogue atomicAdds partials into P[b,h] (P zeroed by k_prep).
__global__ __launch_bounds__(256) void k_main(
    const float* __restrict__ data, const float* __restrict__ b1v,
    const float* __restrict__ b2v, const float* __restrict__ Dv,
    const short* __restrict__ w1T, const short* __restrict__ w2T,
    const float* __restrict__ kkP, float* __restrict__ P)
{
  const int bidx = blockIdx.x, tid = threadIdx.x;
  const int wave = tid >> 6, lane = tid & 63;
  const int quad = lane >> 4, l15 = lane & 15;
  const int bp = bidx >> 6;              // batch pair
  const int lc = bidx & 63;
  const int l0 = lc * 64;

  __shared__ short x1s[2][64 * 136];     // two bf16 x1 tiles (one per batch)

  // ---- Phase A: x1 = relu(data_tile @ w1 + b1) -> LDS, both batches ----
#pragma unroll
  for (int bb = 0; bb < 2; bb++) {
    const int b = bp * 2 + bb;
    const float* dp = data + ((size_t)b * L_LEN + (size_t)(l0 + wave * 16 + l15)) * DIN + quad * 8;
    f32x4 d0 = *(const f32x4*)dp;
    f32x4 d1 = *(const f32x4*)(dp + 4);
    s16x8 af;
    af[0] = f2bf(d0[0]); af[1] = f2bf(d0[1]); af[2] = f2bf(d0[2]); af[3] = f2bf(d0[3]);
    af[4] = f2bf(d1[0]); af[5] = f2bf(d1[1]); af[6] = f2bf(d1[2]); af[7] = f2bf(d1[3]);
#pragma unroll
    for (int c = 0; c < 8; c++) {
      s16x8 bf = *(const s16x8*)(w1T + (c * 16 + l15) * DIN + quad * 8);
      f32x4 a0 = {0.f, 0.f, 0.f, 0.f};
      a0 = __builtin_amdgcn_mfma_f32_16x16x32_bf16(af, bf, a0, 0, 0, 0);
      float bbi = b1v[c * 16 + l15];
#pragma unroll
      for (int r = 0; r < 4; r++) {
        float v = fmaxf(a0[r] + bbi, 0.f);
        x1s[bb][(wave * 16 + quad * 4 + r) * 136 + c * 16 + l15] = f2bf(v);
      }
    }
  }

  // ---- w2 B-fragments in registers (loaded once, reused for both batches) ----
  s16x8 wf[4][4];
#pragma unroll
  for (int ht = 0; ht < 4; ht++)
#pragma unroll
    for (int ks = 0; ks < 4; ks++)
      wf[ht][ks] = *(const s16x8*)(w2T + (wave * 64 + ht * 16 + l15) * J_DIM + ks * 32 + quad * 8);

  __syncthreads();

#pragma unroll 1
  for (int bb = 0; bb < 2; bb++) {
    const int b = bp * 2 + bb;

    f32x4 acc[4][4];
#pragma unroll
    for (int rt = 0; rt < 4; rt++)
#pragma unroll
      for (int ht = 0; ht < 4; ht++)
        acc[rt][ht] = (f32x4){0.f, 0.f, 0.f, 0.f};

    // ---- Phase B: u-tile = x1 @ w2 (64 MFMAs/wave) ----
#pragma unroll
    for (int ks = 0; ks < 4; ks++) {
#pragma unroll
      for (int rt = 0; rt < 4; rt++) {
        s16x8 af = *(const s16x8*)&x1s[bb][(rt * 16 + l15) * 136 + ks * 32 + quad * 8];
#pragma unroll
        for (int ht = 0; ht < 4; ht++)
          acc[rt][ht] = __builtin_amdgcn_mfma_f32_16x16x32_bf16(af, wf[ht][ks], acc[rt][ht], 0, 0, 0);
      }
    }

    // ---- Epilogue: P[b,h] += sum_rows kk*(u+b2) (+ D at l=L-1) ----
#pragma unroll
    for (int ht = 0; ht < 4; ht++) {
      int h = wave * 64 + ht * 16 + l15;   // C-layout: col = lane&15
      float b2h = b2v[h], Dh = Dv[h];
      const f32x4* kp = ((const f32x4*)kkP)
                      + (((lc * 4 + wave) * 4 + ht) * 4) * 64 + lane;
      float s = 0.f;
#pragma unroll
      for (int rt = 0; rt < 4; rt++) {
        f32x4 kv = kp[rt * 64];
#pragma unroll
        for (int r = 0; r < 4; r++) {
          int l = l0 + rt * 16 + quad * 4 + r;   // C-layout: row = quad*4+reg
          float uu = acc[rt][ht][r] + b2h;
          s = fmaf(kv[r], uu, s);
          if (l == L_LEN - 1) s = fmaf(Dh, uu, s);
        }
      }
      s += __shfl_xor(s, 16, 64);
      s += __shfl_xor(s, 32, 64);
      if (quad == 0) atomicAdd(&P[(size_t)b * H_DIM + h], s);
    }
  }
}

// ============ kernel 3a: gelu(P) @ Wg + bg -> GLU -> glu (32x256) ============
// 256 blocks x 1024: block = (b, cg); cg covers a-cols cg*32..+32 and their
// b-col partners +256. 16-way K-split: 16 independent loads/thread.
__global__ __launch_bounds__(1024) void k_mid(
    const float* __restrict__ P, const float* __restrict__ Wg,
    const float* __restrict__ bgv, float* __restrict__ glu)
{
  const int bid = blockIdx.x, t = threadIdx.x;
  const int b = bid >> 3, cg = bid & 7;
  __shared__ float gs[H_DIM];
  __shared__ float part[16][64];
  __shared__ float yy[64];

  if (t < H_DIM) {
    float p = P[b * H_DIM + t];
    gs[t] = 0.5f * p * (1.f + erff(p * 0.70710678118654752f));  // exact gelu
  }
  __syncthreads();

  {
    int ci = t & 63, kc = t >> 6;        // 16 ksplit x 16 j each
    int col = (ci < 32) ? (cg * 32 + ci) : (256 + cg * 32 + (ci - 32));
    float acc = 0.f;
#pragma unroll
    for (int jj = 0; jj < 16; jj++) {
      int j = kc * 16 + jj;
      acc = fmaf(gs[j], Wg[(size_t)j * 512 + col], acc);
    }
    part[kc][ci] = acc;
  }
  __syncthreads();

  if (t < 64) {
    int col = (t < 32) ? (cg * 32 + t) : (256 + cg * 32 + (t - 32));
    float s = bgv[col];
#pragma unroll
    for (int k2 = 0; k2 < 16; k2++) s += part[k2][t];
    yy[t] = s;
  }
  __syncthreads();

  if (t < 32) {
    float a = yy[t], bb = yy[t + 32];
    glu[b * H_DIM + cg * 32 + t] = a * (1.f / (1.f + __expf(-bb)));
  }
}

// ============ kernel 3b: z = relu(glu@w3+b3); out = z@w4+b4 ==================
__global__ __launch_bounds__(1024) void k_fin(
    const float* __restrict__ glu, const float* __restrict__ w3,
    const float* __restrict__ b3v, const float* __restrict__ w4,
    const float* __restrict__ b4v, float* __restrict__ out)
{
  const int b = blockIdx.x, t = threadIdx.x;
  __shared__ float gl[H_DIM];
  __shared__ float zp[8][J_DIM];
  __shared__ float zf[J_DIM];

  if (t < H_DIM) gl[t] = glu[b * H_DIM + t];
  __syncthreads();

  // z = relu(gl @ w3 + b3): 128 cols x 8-way K-split (32 each)
  {
    int col = t & 127, kc = t >> 7;
    const float* wp = w3 + (size_t)(kc * 32) * J_DIM + col;
    float acc = 0.f;
#pragma unroll
    for (int j = 0; j < 32; j++)
      acc = fmaf(gl[kc * 32 + j], wp[(size_t)j * J_DIM], acc);
    zp[kc][col] = acc;
  }
  __syncthreads();
  if (t < J_DIM) {
    float s = b3v[t];
#pragma unroll
    for (int k = 0; k < 8; k++) s += zp[k][t];
    zf[t] = fmaxf(s, 0.f);
  }
  __syncthreads();

  if (t < 16) {
    float s = b4v[t];
#pragma unroll
    for (int i = 0; i < J_DIM; i++)
      s = fmaf(zf[i], w4[i * 16 + t], s);
    out[b * 16 + t] = s;
  }
}

extern "C" void kernel_launch(void* const* d_in, const int* in_sizes, int n_in,
                              void* d_out, int out_size, void* d_ws, size_t ws_size,
                              hipStream_t stream)
{
  const float* data   = (const float*)d_in[0];
  const float* w1     = (const float*)d_in[1];
  const float* b1v    = (const float*)d_in[2];
  const float* w2     = (const float*)d_in[3];
  const float* b2v    = (const float*)d_in[4];
  const float* log_dt = (const float*)d_in[5];
  const float* A_re   = (const float*)d_in[6];
  const float* A_im   = (const float*)d_in[7];
  const float* C_re   = (const float*)d_in[8];
  const float* C_im   = (const float*)d_in[9];
  const float* Dv     = (const float*)d_in[10];
  const float* Wg     = (const float*)d_in[11];
  const float* bgv    = (const float*)d_in[12];
  const float* w3     = (const float*)d_in[13];
  const float* b3v    = (const float*)d_in[14];
  const float* w4     = (const float*)d_in[15];
  const float* b4v    = (const float*)d_in[16];
  float* outp = (float*)d_out;

  // workspace layout (~4.4 MB)
  char* ws = (char*)d_ws;
  float* kkP = (float*)ws;                    // 4 MB (permuted kk)
  float* P   = (float*)(ws + 4194304);        // 32 KB (32 x 256, atomics)
  float* glu = (float*)(ws + 4227072);        // 32 KB (32 x 256)
  short* w1T = (short*)(ws + 4259840);        // 8 KB
  short* w2T = (short*)(ws + 4268032);        // 64 KB

  k_prep<<<1024, 256, 0, stream>>>(w1, w2, log_dt, A_re, A_im, C_re, C_im,
                                   kkP, w1T, w2T, P);
  k_main<<<1024, 256, 0, stream>>>(data, b1v, b2v, Dv, w1T, w2T, kkP, P);
  k_mid<<<256, 1024, 0, stream>>>(P, Wg, bgv, glu);
  k_fin<<<32, 1024, 0, stream>>>(glu, w3, b3v, w4, b4v, outp);
}